// Round 1
// baseline (172.951 us; speedup 1.0000x reference)
//
#include <hip/hip_runtime.h>

// WeightedPairwiseLoss: B=32, N=4096, k=819 (= int(0.2*4096)), outputs 4 f32 scalars.
#define B 32
#define N 4096
#define K 819
#define KP 832          // padded row stride for top/bot arrays
#define SBASE (4*B*KP)  // start of scalar section in ws (floats)
// ws float layout:
//  [0      , B*KP)   top scores
//  [B*KP   , 2*B*KP) top sqrt(weights)
//  [2*B*KP , 3*B*KP) bot scores
//  [3*B*KP , 4*B*KP) bot sqrt(weights)
//  SBASE + 0*B : sumTopSqw[B]
//  SBASE + 1*B : sumBotSqw[B]
//  SBASE + 2*B : bceNum[B]
//  SBASE + 3*B : wmSum[B]
//  SBASE + 4*B : pMaskSum[B]
//  SBASE + 5*B : maskSum[B]
//  SBASE + 6*B : rankPartial[B*4]
// total = 4*32*832 + 192 + 128 = 106816 floats = 427 KB

// Phase 1: per-row bitonic sort of y_rank values (set selection only needs
// thresholds), compact top/bot (score, sqrt(w)) into ws, and all O(N)
// row reductions (BCE, wm, p*mask, mask count, separable w_pair denominator).
__global__ __launch_bounds__(1024) void wpl_phase1(
    const float* __restrict__ scores, const float* __restrict__ p_trade,
    const float* __restrict__ y_rank, const float* __restrict__ y_trade,
    const float* __restrict__ weights, const unsigned char* __restrict__ mask,
    float* __restrict__ ws) {
  const int r = blockIdx.x;
  const int tid = threadIdx.x;
  __shared__ float s[N];           // 16 KB
  __shared__ int cntTop, cntBot;
  __shared__ float red[16 * 6];

  const float* yr = y_rank + r * N;
  for (int i = tid; i < N; i += 1024) s[i] = yr[i];
  if (tid == 0) { cntTop = 0; cntBot = 0; }
  __syncthreads();

  // bitonic sort ascending (values only). XOR formulation: pair (i, i^stride)
  // handled once by the smaller index; barrier between passes.
  for (int size = 2; size <= N; size <<= 1) {
    for (int stride = size >> 1; stride > 0; stride >>= 1) {
      for (int i = tid; i < N; i += 1024) {
        int j = i ^ stride;
        if (j > i) {
          float a = s[i], b = s[j];
          bool up = ((i & size) == 0);
          if (up ? (a > b) : (a < b)) { s[i] = b; s[j] = a; }
        }
      }
      __syncthreads();
    }
  }
  const float t_lo = s[K - 1];     // k-th smallest
  const float t_hi = s[N - K];     // k-th largest

  const float* sc = scores  + r * N;
  const float* wt = weights + r * N;
  const float* pt = p_trade + r * N;
  const float* yt = y_trade + r * N;
  const unsigned char* mk = mask + r * N;
  float* top_s = ws + 0 * B * KP + r * KP;
  float* top_w = ws + 1 * B * KP + r * KP;
  float* bot_s = ws + 2 * B * KP + r * KP;
  float* bot_w = ws + 3 * B * KP + r * KP;

  float a0 = 0, a1 = 0, a2 = 0, a3 = 0, a4 = 0, a5 = 0;
  for (int i = tid; i < N; i += 1024) {
    float y  = yr[i];
    float wv = wt[i];
    float sq = sqrtf(wv);
    float sv = sc[i];
    if (y >= t_hi) {                       // top set (>=k matches; cap at K)
      int pos = atomicAdd(&cntTop, 1);
      if (pos < K) { top_s[pos] = sv; top_w[pos] = sq; a0 += sq; }
    }
    if (y <= t_lo) {                       // bot set
      int pos = atomicAdd(&cntBot, 1);
      if (pos < K) { bot_s[pos] = sv; bot_w[pos] = sq; a1 += sq; }
    }
    float p  = pt[i];
    float m  = mk[i] ? 1.0f : 0.0f;        // numpy bool: 1 byte/elem
    float lp = fmaxf(__logf(p), -100.0f);
    float l1 = fmaxf(log1pf(-p), -100.0f);
    float yv = yt[i];
    float bce = -(yv * lp + (1.0f - yv) * l1);
    float wm = wv * m;
    a2 += bce * wm;
    a3 += wm;
    a4 += p * m;
    a5 += m;
  }

  float vals[6] = {a0, a1, a2, a3, a4, a5};
#pragma unroll
  for (int q = 0; q < 6; q++)
#pragma unroll
    for (int off = 32; off > 0; off >>= 1)
      vals[q] += __shfl_down(vals[q], off);
  const int wave = tid >> 6;
  if ((tid & 63) == 0) {
#pragma unroll
    for (int q = 0; q < 6; q++) red[wave * 6 + q] = vals[q];
  }
  __syncthreads();
  if (tid < 6) {
    float t = 0;
    for (int w2 = 0; w2 < 16; w2++) t += red[w2 * 6 + tid];
    ws[SBASE + tid * B + r] = t;
  }
}

// Phase 2: numerator = sum_i sqw_i * sum_j softplus(s_j - s_i) * sqw_j.
// Grid (4 chunks of top-i, B rows); bot arrays in LDS (broadcast reads).
__global__ __launch_bounds__(256) void wpl_phase2(float* ws) {
  const int c = blockIdx.x;
  const int r = blockIdx.y;
  const int tid = threadIdx.x;
  __shared__ float bs[K];
  __shared__ float bw[K];
  __shared__ float red[4];
  const float* bot_s = ws + 2 * B * KP + r * KP;
  const float* bot_w = ws + 3 * B * KP + r * KP;
  for (int j = tid; j < K; j += 256) { bs[j] = bot_s[j]; bw[j] = bot_w[j]; }
  __syncthreads();

  float acc = 0.0f;
  const int i = c * 256 + tid;
  if (i < K) {
    const float si = ws[0 * B * KP + r * KP + i];
    const float wi = ws[1 * B * KP + r * KP + i];
    for (int j = 0; j < K; j++) {
      float z  = bs[j] - si;                                   // = s_bot - s_top
      float sp = fmaxf(z, 0.0f) + __logf(1.0f + __expf(-fabsf(z)));
      acc += sp * bw[j];
    }
    acc *= wi;
  }
#pragma unroll
  for (int off = 32; off > 0; off >>= 1) acc += __shfl_down(acc, off);
  if ((tid & 63) == 0) red[tid >> 6] = acc;
  __syncthreads();
  if (tid == 0)
    ws[SBASE + 6 * B + r * 4 + c] = red[0] + red[1] + red[2] + red[3];
}

// Phase 3: combine per-row scalars into the 4 outputs.
__global__ __launch_bounds__(64) void wpl_phase3(const float* __restrict__ ws,
                                                 float* __restrict__ out) {
  const int tid = threadIdx.x;
  float lr = 0, lt = 0, ps = 0, ms = 0;
  if (tid < B) {
    const float* pp = ws + SBASE + 6 * B + tid * 4;
    float num = pp[0] + pp[1] + pp[2] + pp[3];
    float den = ws[SBASE + 0 * B + tid] * ws[SBASE + 1 * B + tid] + 1e-8f;
    lr = num / den;
    lt = ws[SBASE + 2 * B + tid] / (ws[SBASE + 3 * B + tid] + 1e-8f);
    ps = ws[SBASE + 4 * B + tid];
    ms = ws[SBASE + 5 * B + tid];
  }
#pragma unroll
  for (int off = 32; off > 0; off >>= 1) {
    lr += __shfl_down(lr, off);
    lt += __shfl_down(lt, off);
    ps += __shfl_down(ps, off);
    ms += __shfl_down(ms, off);
  }
  if (tid == 0) {
    float avg_rank  = lr * (1.0f / B);
    float avg_trade = lt * (1.0f / B);
    out[0] = avg_rank + 0.25f * avg_trade;
    out[1] = avg_rank;
    out[2] = avg_trade;
    out[3] = ps / ms;
  }
}

extern "C" void kernel_launch(void* const* d_in, const int* in_sizes, int n_in,
                              void* d_out, int out_size, void* d_ws, size_t ws_size,
                              hipStream_t stream) {
  const float* scores  = (const float*)d_in[0];
  const float* p_trade = (const float*)d_in[1];
  const float* y_rank  = (const float*)d_in[2];
  const float* y_trade = (const float*)d_in[3];
  const float* weights = (const float*)d_in[4];
  const unsigned char* mask = (const unsigned char*)d_in[5];
  float* out = (float*)d_out;
  float* ws  = (float*)d_ws;

  wpl_phase1<<<B, 1024, 0, stream>>>(scores, p_trade, y_rank, y_trade, weights, mask, ws);
  wpl_phase2<<<dim3(4, B), 256, 0, stream>>>(ws);
  wpl_phase3<<<1, 64, 0, stream>>>(ws, out);
}

// Round 2
// 95.255 us; speedup vs baseline: 1.8157x; 1.8157x over previous
//
#include <hip/hip_runtime.h>

// WeightedPairwiseLoss: B=32, N=4096, k=819 (= int(0.2*4096)), outputs 4 f32 scalars.
#define B 32
#define N 4096
#define K 819
#define KP 832          // padded row stride for top/bot arrays
#define SBASE (4*B*KP)  // start of scalar section in ws (floats)
#define JC 8            // j-chunks in phase2
#define JLEN ((K + JC - 1) / JC)   // 103
// ws float layout:
//  [0      , B*KP)   top scores
//  [B*KP   , 2*B*KP) top sqrt(weights)
//  [2*B*KP , 3*B*KP) bot scores
//  [3*B*KP , 4*B*KP) bot sqrt(weights)
//  SBASE + 0*B : sumTopSqw[B]
//  SBASE + 1*B : sumBotSqw[B]
//  SBASE + 2*B : bceNum[B]
//  SBASE + 3*B : wmSum[B]
//  SBASE + 4*B : pMaskSum[B]
//  SBASE + 5*B : maskSum[B]
//  SBASE + 6*B : rankPartial[B * 4 * JC]

// monotone float->uint key (total order matches float <)
__device__ __forceinline__ unsigned int fkey(float f) {
  unsigned int u = __float_as_uint(f);
  return (u & 0x80000000u) ? ~u : (u | 0x80000000u);
}

// One wave finds the bucket containing 0-based rank R in hist[0..nb) and the
// remaining rank within that bucket. nb must be a multiple of 64.
// Exactly one lane writes the shared outputs.
__device__ __forceinline__ void select_rank(const int* hist, int nb, int R,
                                            int* outBkt, int* outRem) {
  const int lane = threadIdx.x & 63;
  const int G = nb >> 6;           // buckets per lane
  const int base = lane * G;
  int s = 0;
#pragma unroll 8
  for (int q = 0; q < G; q++) s += hist[base + q];
  int inc = s;
#pragma unroll
  for (int off = 1; off < 64; off <<= 1) {
    int v = __shfl_up(inc, off);
    if (lane >= off) inc += v;
  }
  int exc = inc - s;
  if (R >= exc && R < exc + s) {
    int rem = R - exc;
    int b = base;
    while (rem >= hist[b]) { rem -= hist[b]; ++b; }
    *outBkt = b;
    *outRem = rem;
  }
}

// Phase 1: 3-level radix select (exact rank K-1 and N-K keys of y_rank),
// compact top/bot (score, sqrt(w)) into ws, and all O(N) row reductions.
__global__ __launch_bounds__(1024) void wpl_phase1(
    const float* __restrict__ scores, const float* __restrict__ p_trade,
    const float* __restrict__ y_rank, const float* __restrict__ y_trade,
    const float* __restrict__ weights, const unsigned char* __restrict__ mask,
    float* __restrict__ ws) {
  const int r = blockIdx.x;
  const int tid = threadIdx.x;
  __shared__ unsigned int skey[N];   // 16 KB
  __shared__ int hist1[2048];        // lvl1 histogram; reused as lvl3 A|B halves
  __shared__ int histA[2048];        // lvl2 for rank A (t_lo)
  __shared__ int histB[2048];        // lvl2 for rank B (t_hi)
  __shared__ int sBktA, sRemA, sBktB, sRemB;
  __shared__ int sSubA, sRemA2, sSubB, sRemB2;
  __shared__ int sB3A, sB3B, sDumA, sDumB;
  __shared__ int cntTop, cntBot;
  __shared__ float red[16 * 6];

  const float4* yr4 = (const float4*)(y_rank + r * N);

  // step 1: load+transform keys, clear all histograms
  {
    float4 y = yr4[tid];
    skey[tid * 4 + 0] = fkey(y.x);
    skey[tid * 4 + 1] = fkey(y.y);
    skey[tid * 4 + 2] = fkey(y.z);
    skey[tid * 4 + 3] = fkey(y.w);
  }
  hist1[tid] = 0; hist1[tid + 1024] = 0;
  histA[tid] = 0; histA[tid + 1024] = 0;
  histB[tid] = 0; histB[tid + 1024] = 0;
  if (tid == 0) { cntTop = 0; cntBot = 0; }
  __syncthreads();

  // step 2: level-1 histogram (top 11 bits)
#pragma unroll
  for (int q = 0; q < 4; q++)
    atomicAdd(&hist1[skey[tid * 4 + q] >> 21], 1);
  __syncthreads();

  // step 3: level-1 select. Rank A = K-1 (t_lo), rank B = N-K (t_hi).
  if (tid < 64)       select_rank(hist1, 2048, K - 1, &sBktA, &sRemA);
  else if (tid < 128) select_rank(hist1, 2048, N - K, &sBktB, &sRemB);
  __syncthreads();

  // step 4: clear hist1 (for lvl3 reuse) + fill level-2 histograms
  hist1[tid] = 0; hist1[tid + 1024] = 0;
  {
    const int bA = sBktA, bB = sBktB;
#pragma unroll
    for (int q = 0; q < 4; q++) {
      unsigned int key = skey[tid * 4 + q];
      int top11 = key >> 21;
      int mid11 = (key >> 10) & 0x7FF;
      if (top11 == bA) atomicAdd(&histA[mid11], 1);
      if (top11 == bB) atomicAdd(&histB[mid11], 1);
    }
  }
  __syncthreads();

  // step 5: level-2 select
  if (tid < 64)       select_rank(histA, 2048, sRemA, &sSubA, &sRemA2);
  else if (tid < 128) select_rank(histB, 2048, sRemB, &sSubB, &sRemB2);
  __syncthreads();

  // step 6: level-3 histogram (low 10 bits) into hist1 halves
  {
    const unsigned int prefA = ((unsigned)sBktA << 11) | (unsigned)sSubA;
    const unsigned int prefB = ((unsigned)sBktB << 11) | (unsigned)sSubB;
#pragma unroll
    for (int q = 0; q < 4; q++) {
      unsigned int key = skey[tid * 4 + q];
      unsigned int pref = key >> 10;
      int low10 = key & 0x3FF;
      if (pref == prefA) atomicAdd(&hist1[low10], 1);
      if (pref == prefB) atomicAdd(&hist1[1024 + low10], 1);
    }
  }
  __syncthreads();

  // step 7: level-3 select -> exact threshold keys
  if (tid < 64)       select_rank(hist1, 1024, sRemA2, &sB3A, &sDumA);
  else if (tid < 128) select_rank(hist1 + 1024, 1024, sRemB2, &sB3B, &sDumB);
  __syncthreads();

  const unsigned int keyA = ((unsigned)sBktA << 21) | ((unsigned)sSubA << 10) | (unsigned)sB3A; // t_lo
  const unsigned int keyB = ((unsigned)sBktB << 21) | ((unsigned)sSubB << 10) | (unsigned)sB3B; // t_hi

  // step 8: compaction + O(N) reductions (vectorized loads)
  const float* sc = scores  + r * N;
  const float* wt = weights + r * N;
  const float* pt = p_trade + r * N;
  const float* yt = y_trade + r * N;
  const unsigned char* mk = mask + r * N;
  float* top_s = ws + 0 * B * KP + r * KP;
  float* top_w = ws + 1 * B * KP + r * KP;
  float* bot_s = ws + 2 * B * KP + r * KP;
  float* bot_w = ws + 3 * B * KP + r * KP;

  float4 s4 = ((const float4*)sc)[tid];
  float4 w4 = ((const float4*)wt)[tid];
  float4 p4 = ((const float4*)pt)[tid];
  float4 t4 = ((const float4*)yt)[tid];
  uchar4 m4 = ((const uchar4*)mk)[tid];
  const float sv[4] = {s4.x, s4.y, s4.z, s4.w};
  const float wv[4] = {w4.x, w4.y, w4.z, w4.w};
  const float pv[4] = {p4.x, p4.y, p4.z, p4.w};
  const float tv[4] = {t4.x, t4.y, t4.z, t4.w};
  const unsigned char mv[4] = {m4.x, m4.y, m4.z, m4.w};

  float a0 = 0, a1 = 0, a2 = 0, a3 = 0, a4 = 0, a5 = 0;
#pragma unroll
  for (int q = 0; q < 4; q++) {
    unsigned int key = skey[tid * 4 + q];
    float w  = wv[q];
    float sq = sqrtf(w);
    if (key >= keyB) {                     // top set (cap at K for ties)
      int pos = atomicAdd(&cntTop, 1);
      if (pos < K) { top_s[pos] = sv[q]; top_w[pos] = sq; a0 += sq; }
    }
    if (key <= keyA) {                     // bot set
      int pos = atomicAdd(&cntBot, 1);
      if (pos < K) { bot_s[pos] = sv[q]; bot_w[pos] = sq; a1 += sq; }
    }
    float p  = pv[q];
    float m  = mv[q] ? 1.0f : 0.0f;
    float lp = fmaxf(__logf(p), -100.0f);
    float l1 = fmaxf(log1pf(-p), -100.0f);
    float yv = tv[q];
    float bce = -(yv * lp + (1.0f - yv) * l1);
    float wm = w * m;
    a2 += bce * wm;
    a3 += wm;
    a4 += p * m;
    a5 += m;
  }

  float vals[6] = {a0, a1, a2, a3, a4, a5};
#pragma unroll
  for (int q = 0; q < 6; q++)
#pragma unroll
    for (int off = 32; off > 0; off >>= 1)
      vals[q] += __shfl_down(vals[q], off);
  const int wave = tid >> 6;
  if ((tid & 63) == 0) {
#pragma unroll
    for (int q = 0; q < 6; q++) red[wave * 6 + q] = vals[q];
  }
  __syncthreads();
  if (tid < 6) {
    float t = 0;
    for (int w2 = 0; w2 < 16; w2++) t += red[w2 * 6 + tid];
    ws[SBASE + tid * B + r] = t;
  }
}

// Phase 2: numerator = sum_i sqw_i * sum_j softplus(s_j - s_i) * sqw_j.
// Grid (4 i-chunks, JC j-chunks, B rows) = 1024 blocks; bot slice in LDS.
__global__ __launch_bounds__(256) void wpl_phase2(float* ws) {
  const int ci = blockIdx.x;
  const int cj = blockIdx.y;
  const int r  = blockIdx.z;
  const int tid = threadIdx.x;
  __shared__ float bs[JLEN];
  __shared__ float bw[JLEN];
  __shared__ float red[4];
  const int j0 = cj * JLEN;
  const int jn = min(K - j0, JLEN);
  const float* bot_s = ws + 2 * B * KP + r * KP + j0;
  const float* bot_w = ws + 3 * B * KP + r * KP + j0;
  for (int j = tid; j < jn; j += 256) { bs[j] = bot_s[j]; bw[j] = bot_w[j]; }
  __syncthreads();

  float acc = 0.0f;
  const int i = ci * 256 + tid;
  if (i < K) {
    const float si = ws[0 * B * KP + r * KP + i];
    const float wi = ws[1 * B * KP + r * KP + i];
#pragma unroll 4
    for (int j = 0; j < jn; j++) {
      float z  = bs[j] - si;                                   // = s_bot - s_top
      float sp = fmaxf(z, 0.0f) + __logf(1.0f + __expf(-fabsf(z)));
      acc += sp * bw[j];
    }
    acc *= wi;
  }
#pragma unroll
  for (int off = 32; off > 0; off >>= 1) acc += __shfl_down(acc, off);
  if ((tid & 63) == 0) red[tid >> 6] = acc;
  __syncthreads();
  if (tid == 0)
    ws[SBASE + 6 * B + (r * 4 + ci) * JC + cj] = red[0] + red[1] + red[2] + red[3];
}

// Phase 3: combine per-row scalars into the 4 outputs.
__global__ __launch_bounds__(64) void wpl_phase3(const float* __restrict__ ws,
                                                 float* __restrict__ out) {
  const int tid = threadIdx.x;
  float lr = 0, lt = 0, ps = 0, ms = 0;
  if (tid < B) {
    const float* pp = ws + SBASE + 6 * B + tid * 4 * JC;
    float num = 0;
#pragma unroll
    for (int q = 0; q < 4 * JC; q++) num += pp[q];
    float den = ws[SBASE + 0 * B + tid] * ws[SBASE + 1 * B + tid] + 1e-8f;
    lr = num / den;
    lt = ws[SBASE + 2 * B + tid] / (ws[SBASE + 3 * B + tid] + 1e-8f);
    ps = ws[SBASE + 4 * B + tid];
    ms = ws[SBASE + 5 * B + tid];
  }
#pragma unroll
  for (int off = 32; off > 0; off >>= 1) {
    lr += __shfl_down(lr, off);
    lt += __shfl_down(lt, off);
    ps += __shfl_down(ps, off);
    ms += __shfl_down(ms, off);
  }
  if (tid == 0) {
    float avg_rank  = lr * (1.0f / B);
    float avg_trade = lt * (1.0f / B);
    out[0] = avg_rank + 0.25f * avg_trade;
    out[1] = avg_rank;
    out[2] = avg_trade;
    out[3] = ps / ms;
  }
}

extern "C" void kernel_launch(void* const* d_in, const int* in_sizes, int n_in,
                              void* d_out, int out_size, void* d_ws, size_t ws_size,
                              hipStream_t stream) {
  const float* scores  = (const float*)d_in[0];
  const float* p_trade = (const float*)d_in[1];
  const float* y_rank  = (const float*)d_in[2];
  const float* y_trade = (const float*)d_in[3];
  const float* weights = (const float*)d_in[4];
  const unsigned char* mask = (const unsigned char*)d_in[5];
  float* out = (float*)d_out;
  float* ws  = (float*)d_ws;

  wpl_phase1<<<B, 1024, 0, stream>>>(scores, p_trade, y_rank, y_trade, weights, mask, ws);
  wpl_phase2<<<dim3(4, JC, B), 256, 0, stream>>>(ws);
  wpl_phase3<<<1, 64, 0, stream>>>(ws, out);
}

// Round 3
// 92.699 us; speedup vs baseline: 1.8657x; 1.0276x over previous
//
#include <hip/hip_runtime.h>

// WeightedPairwiseLoss: B=32, N=4096, k=819 (= int(0.2*4096)), outputs 4 f32 scalars.
#define B 32
#define N 4096
#define K 819
#define KP 832                 // padded row stride; KP = JC2*JL2 exactly
#define SBASE (4*B*KP)         // scalar section start (floats)
#define JC2 32                 // j-chunks in phase2
#define JL2 26                 // j per chunk (32*26 = 832)
// ws layout (float2 view for pair arrays):
//  float2 [0      , B*KP)   : top (score, sqrtw), row stride KP, padded w=0
//  float2 [B*KP   , 2*B*KP) : bot (score, sqrtw)
//  float  SBASE + 0*B : sumTopSqw[B]
//  float  SBASE + 1*B : sumBotSqw[B]
//  float  SBASE + 2*B : bceNum[B]
//  float  SBASE + 3*B : wmSum[B]
//  float  SBASE + 4*B : pMaskSum[B]
//  float  SBASE + 5*B : maskSum[B]
//  float  SBASE + 6*B : rankPartial[B * JC2]

// One wave: find bucket containing 0-based rank R in hist[0..2048) and the
// remaining rank inside it. Bucket walk happens in REGISTERS (no dependent
// LDS chain). Exactly one lane writes the outputs.
__device__ __forceinline__ void select_bucket(const int* hist, int R,
                                              int* outBkt, int* outRem) {
  const int lane = threadIdx.x & 63;
  int cnt[32];
  int s = 0;
#pragma unroll
  for (int q = 0; q < 32; q++) { cnt[q] = hist[lane * 32 + q]; s += cnt[q]; }
  int inc = s;
#pragma unroll
  for (int off = 1; off < 64; off <<= 1) {
    int v = __shfl_up(inc, off);
    if (lane >= off) inc += v;
  }
  int exc = inc - s;
  if (R >= exc && R < exc + s) {
    int rem = R - exc, b = 0;
#pragma unroll
    for (int q = 0; q < 32; q++)
      if (b == q && rem >= cnt[q]) { rem -= cnt[q]; b = q + 1; }
    *outBkt = lane * 32 + b;
    *outRem = rem;
  }
}

// One wave: pick the rem-th smallest of cand[0..c) (c <= 64) via shuffle
// all-pairs ranking; the winning lane writes *out.
__device__ __forceinline__ void pick_kth(const float* cand, int c, int rem,
                                         float* out) {
  const int lane = threadIdx.x & 63;
  float v = (lane < c) ? cand[lane] : 3.4e38f;
  int rk = 0;
#pragma unroll 8
  for (int m = 0; m < 64; m++) {
    float u = __shfl(v, m);
    rk += (u < v || (u == v && m < lane)) ? 1 : 0;
  }
  if (lane < c && rk == rem) *out = v;
}

// Phase 1: per-row exact rank-(K-1) and rank-(N-K) thresholds of y_rank via
// ONE value-linear 2048-bucket histogram + tiny candidate set; then compact
// top/bot (score, sqrtw) pairs and all O(N) row reductions.
__global__ __launch_bounds__(1024) void wpl_phase1(
    const float* __restrict__ scores, const float* __restrict__ p_trade,
    const float* __restrict__ y_rank, const float* __restrict__ y_trade,
    const float* __restrict__ weights, const unsigned char* __restrict__ mask,
    float* __restrict__ ws) {
  const int r = blockIdx.x;
  const int tid = threadIdx.x;
  __shared__ int hist[2048];
  __shared__ float redMn[16], redMx[16];
  __shared__ float red[16 * 6];
  __shared__ float sMn, sScale, sTlo, sThi;
  __shared__ float candA[64], candB[64];
  __shared__ int cA, cB, cntTop, cntBot;
  __shared__ int bktA, remA, bktB, remB;

  // ---- load everything for this row into registers (vectorized) ----
  const float4 y4 = ((const float4*)(y_rank  + r * N))[tid];
  const float4 s4 = ((const float4*)(scores  + r * N))[tid];
  const float4 w4 = ((const float4*)(weights + r * N))[tid];
  const float4 p4 = ((const float4*)(p_trade + r * N))[tid];
  const float4 t4 = ((const float4*)(y_trade + r * N))[tid];
  const uchar4 m4 = ((const uchar4*)(mask    + r * N))[tid];
  const float yv[4] = {y4.x, y4.y, y4.z, y4.w};
  const float sv[4] = {s4.x, s4.y, s4.z, s4.w};
  const float wv[4] = {w4.x, w4.y, w4.z, w4.w};
  const float pv[4] = {p4.x, p4.y, p4.z, p4.w};
  const float tv[4] = {t4.x, t4.y, t4.z, t4.w};
  const unsigned char mv[4] = {m4.x, m4.y, m4.z, m4.w};

  // ---- step 1: clear hist, row min/max reduce ----
  hist[tid] = 0; hist[tid + 1024] = 0;
  if (tid == 0) { cA = 0; cB = 0; cntTop = 0; cntBot = 0; }
  float mn = fminf(fminf(yv[0], yv[1]), fminf(yv[2], yv[3]));
  float mx = fmaxf(fmaxf(yv[0], yv[1]), fmaxf(yv[2], yv[3]));
#pragma unroll
  for (int off = 32; off > 0; off >>= 1) {
    mn = fminf(mn, __shfl_down(mn, off));
    mx = fmaxf(mx, __shfl_down(mx, off));
  }
  if ((tid & 63) == 0) { redMn[tid >> 6] = mn; redMx[tid >> 6] = mx; }
  __syncthreads();
  if (tid == 0) {
    float a = redMn[0], b = redMx[0];
    for (int q = 1; q < 16; q++) { a = fminf(a, redMn[q]); b = fmaxf(b, redMx[q]); }
    sMn = a;
    sScale = 2048.0f / (b - a + 1e-20f);
  }
  __syncthreads();

  // ---- step 2: linear histogram ----
  const float bmn = sMn, bsc = sScale;
#pragma unroll
  for (int q = 0; q < 4; q++) {
    int bkt = (int)((yv[q] - bmn) * bsc);
    bkt = min(2047, max(0, bkt));
    atomicAdd(&hist[bkt], 1);
  }
  __syncthreads();

  // ---- step 3: find rank buckets (two waves in parallel) ----
  if (tid < 64)       select_bucket(hist, K - 1, &bktA, &remA);   // t_lo
  else if (tid < 128) select_bucket(hist, N - K, &bktB, &remB);   // t_hi
  __syncthreads();

  // ---- step 4: gather candidates from the two rank buckets ----
  {
    const int bA = bktA, bB = bktB;
#pragma unroll
    for (int q = 0; q < 4; q++) {
      int bkt = (int)((yv[q] - bmn) * bsc);
      bkt = min(2047, max(0, bkt));
      if (bkt == bA) { int p = atomicAdd(&cA, 1); if (p < 64) candA[p] = yv[q]; }
      if (bkt == bB) { int p = atomicAdd(&cB, 1); if (p < 64) candB[p] = yv[q]; }
    }
  }
  __syncthreads();

  // ---- step 5: exact thresholds from candidates ----
  if (tid < 64)       pick_kth(candA, cA, remA, &sTlo);
  else if (tid < 128) pick_kth(candB, cB, remB, &sThi);
  __syncthreads();
  const float t_lo = sTlo, t_hi = sThi;

  // ---- step 6: compaction + O(N) reductions ----
  float2* top = (float2*)ws + (size_t)r * KP;
  float2* bot = (float2*)ws + (size_t)(B + r) * KP;
  if (tid < KP - K) {            // zero the pads (phase2 runs static loops)
    top[K + tid] = make_float2(0.0f, 0.0f);
    bot[K + tid] = make_float2(0.0f, 0.0f);
  }

  float a0 = 0, a1 = 0, a2 = 0, a3 = 0, a4 = 0, a5 = 0;
#pragma unroll
  for (int q = 0; q < 4; q++) {
    float w  = wv[q];
    float sq = sqrtf(w);
    if (yv[q] >= t_hi) {                   // top set (cap K for ties)
      int pos = atomicAdd(&cntTop, 1);
      if (pos < K) { top[pos] = make_float2(sv[q], sq); a0 += sq; }
    }
    if (yv[q] <= t_lo) {                   // bot set
      int pos = atomicAdd(&cntBot, 1);
      if (pos < K) { bot[pos] = make_float2(sv[q], sq); a1 += sq; }
    }
    float p  = pv[q];
    float m  = mv[q] ? 1.0f : 0.0f;
    float lp = fmaxf(__logf(p), -100.0f);
    float l1 = fmaxf(log1pf(-p), -100.0f);
    float bce = -(tv[q] * lp + (1.0f - tv[q]) * l1);
    float wm = w * m;
    a2 += bce * wm;
    a3 += wm;
    a4 += p * m;
    a5 += m;
  }

  float vals[6] = {a0, a1, a2, a3, a4, a5};
#pragma unroll
  for (int q = 0; q < 6; q++)
#pragma unroll
    for (int off = 32; off > 0; off >>= 1)
      vals[q] += __shfl_down(vals[q], off);
  const int wave = tid >> 6;
  if ((tid & 63) == 0) {
#pragma unroll
    for (int q = 0; q < 6; q++) red[wave * 6 + q] = vals[q];
  }
  __syncthreads();
  if (tid < 6) {
    float t = 0;
    for (int w2 = 0; w2 < 16; w2++) t += red[w2 * 6 + tid];
    ws[SBASE + tid * B + r] = t;
  }
}

// Phase 2: numerator = sum_i sqw_i * sum_j softplus(s_j - s_i) * sqw_j.
// Grid (JC2, B) = 1024 blocks; each thread register-blocks 4 i-values so the
// per-pair LDS read cost is amortized 4x. All loops static (pads have w=0).
__global__ __launch_bounds__(256) void wpl_phase2(float* __restrict__ ws) {
  const int cj = blockIdx.x;
  const int r  = blockIdx.y;
  const int tid = threadIdx.x;
  __shared__ float2 bsw[JL2];
  __shared__ float red[4];
  const float2* top = (const float2*)ws + (size_t)r * KP;
  const float2* bot = (const float2*)ws + (size_t)(B + r) * KP;
  if (tid < JL2) bsw[tid] = bot[cj * JL2 + tid];
  __syncthreads();

  float acc = 0.0f;
#pragma unroll
  for (int q = 0; q < 4; q++) {
    const int i = q * 256 + tid;
    float2 sw = (i < KP) ? top[i] : make_float2(0.0f, 0.0f);
    float a = 0.0f;
#pragma unroll
    for (int j = 0; j < JL2; j++) {
      float z  = bsw[j].x - sw.x;                              // s_bot - s_top
      float sp = fmaxf(z, 0.0f) + __logf(1.0f + __expf(-fabsf(z)));
      a += sp * bsw[j].y;
    }
    acc += a * sw.y;
  }
#pragma unroll
  for (int off = 32; off > 0; off >>= 1) acc += __shfl_down(acc, off);
  if ((tid & 63) == 0) red[tid >> 6] = acc;
  __syncthreads();
  if (tid == 0)
    ws[SBASE + 6 * B + r * JC2 + cj] = red[0] + red[1] + red[2] + red[3];
}

// Phase 3: combine per-row scalars into the 4 outputs.
__global__ __launch_bounds__(64) void wpl_phase3(const float* __restrict__ ws,
                                                 float* __restrict__ out) {
  const int tid = threadIdx.x;
  float lr = 0, lt = 0, ps = 0, ms = 0;
  if (tid < B) {
    const float* pp = ws + SBASE + 6 * B + tid * JC2;
    float num = 0;
#pragma unroll
    for (int q = 0; q < JC2; q++) num += pp[q];
    float den = ws[SBASE + 0 * B + tid] * ws[SBASE + 1 * B + tid] + 1e-8f;
    lr = num / den;
    lt = ws[SBASE + 2 * B + tid] / (ws[SBASE + 3 * B + tid] + 1e-8f);
    ps = ws[SBASE + 4 * B + tid];
    ms = ws[SBASE + 5 * B + tid];
  }
#pragma unroll
  for (int off = 32; off > 0; off >>= 1) {
    lr += __shfl_down(lr, off);
    lt += __shfl_down(lt, off);
    ps += __shfl_down(ps, off);
    ms += __shfl_down(ms, off);
  }
  if (tid == 0) {
    float avg_rank  = lr * (1.0f / B);
    float avg_trade = lt * (1.0f / B);
    out[0] = avg_rank + 0.25f * avg_trade;
    out[1] = avg_rank;
    out[2] = avg_trade;
    out[3] = ps / ms;
  }
}

extern "C" void kernel_launch(void* const* d_in, const int* in_sizes, int n_in,
                              void* d_out, int out_size, void* d_ws, size_t ws_size,
                              hipStream_t stream) {
  const float* scores  = (const float*)d_in[0];
  const float* p_trade = (const float*)d_in[1];
  const float* y_rank  = (const float*)d_in[2];
  const float* y_trade = (const float*)d_in[3];
  const float* weights = (const float*)d_in[4];
  const unsigned char* mask = (const unsigned char*)d_in[5];
  float* out = (float*)d_out;
  float* ws  = (float*)d_ws;

  wpl_phase1<<<B, 1024, 0, stream>>>(scores, p_trade, y_rank, y_trade, weights, mask, ws);
  wpl_phase2<<<dim3(JC2, B), 256, 0, stream>>>(ws);
  wpl_phase3<<<1, 64, 0, stream>>>(ws, out);
}